// Round 2
// baseline (467.916 us; speedup 1.0000x reference)
//
#include <hip/hip_runtime.h>

typedef __attribute__((ext_vector_type(8))) short short8;
typedef __attribute__((ext_vector_type(4))) float f32x4;
typedef unsigned short u16;
typedef unsigned int u32;

__device__ __forceinline__ void gld_lds16(const void* g, void* l) {
  __builtin_amdgcn_global_load_lds((const __attribute__((address_space(1))) void*)g,
                                   (__attribute__((address_space(3))) void*)l,
                                   16, 0, 0);
}

__device__ __forceinline__ u16 f2b(float x) {
  union { float f; u32 u; } v; v.f = x;
  u32 u = v.u;
  return (u16)((u + 0x7FFFu + ((u >> 16) & 1u)) >> 16);
}
__device__ __forceinline__ float b2f(u16 x) {
  union { u32 u; float f; } v; v.u = ((u32)x) << 16; return v.f;
}
__device__ __forceinline__ u32 pack_pair(float lo, float hi) {
  return (u32)f2b(lo) | ((u32)f2b(hi) << 16);
}

// ---- weight pack (fp32 -> bf16): Wd/Wu (co,ci,k)->(k,co,ci); Wg -> Wg^T ----
__global__ __launch_bounds__(256) void k_pack(const float* __restrict__ Wd, const float* __restrict__ Wg,
                                              const float* __restrict__ Wu,
                                              u16* __restrict__ Wdp, u16* __restrict__ WgT,
                                              u16* __restrict__ Wup) {
  int id = blockIdx.x * 256 + threadIdx.x;
  if (id < 196608) {
    int kk = id >> 16;
    int rem = id & 65535;
    int co = rem >> 8, ci = rem & 255;
    u32 s = (u32)co * 768 + (u32)ci * 3 + kk;
    Wdp[id] = f2b(Wd[s]);
    Wup[id] = f2b(Wu[s]);
  } else {
    int id2 = id - 196608;
    int j = id2 >> 8, i = id2 & 255;
    WgT[id2] = f2b(Wg[i * 256 + j]);
  }
}

// ---- transpose+cast x[tl][ci][p] (fp32) -> xT[tl][p][ci] (bf16) ----
__global__ __launch_bounds__(256) void k_transpose(const float* __restrict__ x, u16* __restrict__ xT) {
  __shared__ u16 tile[64][72];
  int blk = blockIdx.x;
  int tl = blk >> 4;
  int sub = blk & 15;
  int ci0 = (sub >> 2) << 6;
  int p0 = (sub & 3) << 6;
  int tid = threadIdx.x;
  int i = tid >> 2;
  int ch = tid & 3;
  const float* gsrc = x + (size_t)tl * 65536 + (ci0 + i) * 256 + p0 + ch * 16;
  __align__(16) u16 cv[16];
#pragma unroll
  for (int v4 = 0; v4 < 4; ++v4) {
    float4 f = *(const float4*)(gsrc + v4 * 4);
    cv[v4 * 4 + 0] = f2b(f.x);
    cv[v4 * 4 + 1] = f2b(f.y);
    cv[v4 * 4 + 2] = f2b(f.z);
    cv[v4 * 4 + 3] = f2b(f.w);
  }
  *(uint4*)&tile[i][ch * 16] = *(const uint4*)&cv[0];
  *(uint4*)&tile[i][ch * 16 + 8] = *(const uint4*)&cv[8];
  __syncthreads();
  __align__(16) u16 tmp[16];
#pragma unroll
  for (int cc = 0; cc < 16; ++cc) tmp[cc] = tile[ch * 16 + cc][i];
  u16* gdst = xT + (size_t)tl * 65536 + (p0 + i) * 256 + ci0 + ch * 16;
  *(uint4*)(gdst) = *(const uint4*)&tmp[0];
  *(uint4*)(gdst + 8) = *(const uint4*)&tmp[8];
}

// ---------------- GEMM building blocks (m97 structure) ----------------
__device__ __forceinline__ void stage_tile(const u16* __restrict__ g, int ldg, u16* s, int w, int lane) {
  int r = lane >> 2;
  int cc = (lane & 3) * 8;
#pragma unroll
  for (int j = 0; j < 2; ++j) {
    gld_lds16(g + (w * 32 + j * 16 + r) * ldg + cc, s + (w * 32 + j * 16) * 32);
  }
}

__device__ __forceinline__ void mfma_tiles(const u16* sA, const u16* sB, f32x4 acc[4][4],
                                           int wr, int wc, int lane) {
  int m16 = lane & 15;
  int q8 = (lane >> 4) * 8;
  short8 a[4], b[4];
#pragma unroll
  for (int mi = 0; mi < 4; ++mi) a[mi] = *(const short8*)(sA + (wr * 64 + mi * 16 + m16) * 32 + q8);
#pragma unroll
  for (int ni = 0; ni < 4; ++ni) b[ni] = *(const short8*)(sB + (wc * 64 + ni * 16 + m16) * 32 + q8);
#pragma unroll
  for (int mi = 0; mi < 4; ++mi)
#pragma unroll
    for (int ni = 0; ni < 4; ++ni)
      acc[mi][ni] = __builtin_amdgcn_mfma_f32_16x16x32_bf16(a[mi], b[ni], acc[mi][ni], 0, 0, 0);
}

// bf16 pair store: lane pair (c even, c+1) covers rows row0..row0+3 at dword colb
__device__ __forceinline__ void store_pairs(u16* base, int row0, int stride, int colb,
                                            const float v[4], bool ev) {
  float pv[4];
#pragma unroll
  for (int r = 0; r < 4; ++r) pv[r] = __shfl_xor(v[r], 1, 64);
  u32 wd0 = ev ? pack_pair(v[0], pv[0]) : pack_pair(pv[0], v[0]);
  u32 wd1 = ev ? pack_pair(v[1], pv[1]) : pack_pair(pv[1], v[1]);
  u32 wd2 = ev ? pack_pair(v[2], pv[2]) : pack_pair(pv[2], v[2]);
  u32 wd3 = ev ? pack_pair(v[3], pv[3]) : pack_pair(pv[3], v[3]);
  u32 wa = ev ? wd0 : wd2;
  u32 wb = ev ? wd1 : wd3;
  int rs = ev ? 0 : 2;
  *(u32*)(base + (size_t)(row0 + rs) * stride + colb) = wa;
  *(u32*)(base + (size_t)(row0 + rs + 1) * stride + colb) = wb;
}

// fp32 pair store (float2 per row)
__device__ __forceinline__ void store_pairs_f32(float* base, int row0, int stride, int colb,
                                                const float v[4], bool ev) {
  float pv[4];
#pragma unroll
  for (int r = 0; r < 4; ++r) pv[r] = __shfl_xor(v[r], 1, 64);
  float2 wa, wb;
  if (ev) { wa = make_float2(v[0], pv[0]); wb = make_float2(v[1], pv[1]); }
  else    { wa = make_float2(pv[2], v[2]); wb = make_float2(pv[3], v[3]); }
  int rs = ev ? 0 : 2;
  *(float2*)(base + (size_t)(row0 + rs) * stride + colb) = wa;
  *(float2*)(base + (size_t)(row0 + rs + 1) * stride + colb) = wb;
}

// ---- G1: nodes[bt][p][co] = tconv1(x)*s1 + t1 (bf16) ----
__global__ __launch_bounds__(256) void k_g1(const u16* __restrict__ xT, const u16* __restrict__ Wdp,
                                            const float* __restrict__ s1, const float* __restrict__ t1,
                                            u16* __restrict__ nodes) {
  __shared__ u16 sA[128 * 32];
  __shared__ u16 sB[128 * 32];
  int blk = blockIdx.x;
  int bt = blk >> 2;
  int tile = blk & 3;
  int tm = tile >> 1, tn = tile & 1;
  int t = bt & 127;
  int tid = threadIdx.x, lane = tid & 63, w = tid >> 6;
  int wr = w >> 1, wc = w & 1;
  f32x4 acc[4][4];
#pragma unroll
  for (int i = 0; i < 4; ++i)
#pragma unroll
    for (int j = 0; j < 4; ++j) acc[i][j] = (f32x4){0.f, 0.f, 0.f, 0.f};

#pragma unroll
  for (int kk = 0; kk < 3; ++kk) {
    int tp = t - 1 + kk;
    if (tp < 0 || tp > 127) continue;
    const u16* gA = xT + ((size_t)(bt - t + tp) * 256 + tm * 128) * 256;
    const u16* gB = Wdp + (size_t)kk * 65536 + (tn * 128) * 256;
    for (int ks = 0; ks < 8; ++ks) {
      stage_tile(gA + ks * 32, 256, sA, w, lane);
      stage_tile(gB + ks * 32, 256, sB, w, lane);
      __syncthreads();
      mfma_tiles(sA, sB, acc, wr, wc, lane);
      __syncthreads();
    }
  }
  int q = lane >> 4, c = lane & 15;
  bool ev = (lane & 1) == 0;
  float s1v[4], t1v[4];
#pragma unroll
  for (int ni = 0; ni < 4; ++ni) {
    int co = tn * 128 + wc * 64 + ni * 16 + c;
    s1v[ni] = s1[co];
    t1v[ni] = t1[co];
  }
  u16* obase = nodes + (size_t)bt * 65536;
#pragma unroll
  for (int mi = 0; mi < 4; ++mi) {
    int row0 = tm * 128 + wr * 64 + mi * 16 + q * 4;
#pragma unroll
    for (int ni = 0; ni < 4; ++ni) {
      float v[4];
#pragma unroll
      for (int r = 0; r < 4; ++r) v[r] = acc[mi][ni][r] * s1v[ni] + t1v[ni];
      int colb = tn * 128 + wc * 64 + ni * 16 + (c & ~1);
      store_pairs(obase, row0, 256, colb, v, ev);
    }
  }
}

// ---- G2: out_pre = nodes @ Wg + bg (bf16); side-dump raw xl (fp32) for p<4 ----
__global__ __launch_bounds__(256) void k_g2(const u16* __restrict__ nodes, const u16* __restrict__ WgT,
                                            const float* __restrict__ bg,
                                            u16* __restrict__ outp, float* __restrict__ edge) {
  __shared__ u16 sA[128 * 32];
  __shared__ u16 sB[128 * 32];
  int blk = blockIdx.x;
  int mt = blk >> 1;
  int nt = blk & 1;
  int m0 = mt * 128;
  int tid = threadIdx.x, lane = tid & 63, w = tid >> 6;
  int wr = w >> 1, wc = w & 1;
  f32x4 acc[4][4];
#pragma unroll
  for (int i = 0; i < 4; ++i)
#pragma unroll
    for (int j = 0; j < 4; ++j) acc[i][j] = (f32x4){0.f, 0.f, 0.f, 0.f};

  const u16* gA = nodes + (size_t)m0 * 256;
  const u16* gB = WgT + (size_t)(nt * 128) * 256;
  for (int ks = 0; ks < 8; ++ks) {
    stage_tile(gA + ks * 32, 256, sA, w, lane);
    stage_tile(gB + ks * 32, 256, sB, w, lane);
    __syncthreads();
    mfma_tiles(sA, sB, acc, wr, wc, lane);
    __syncthreads();
  }
  int q = lane >> 4, c = lane & 15;
  bool ev = (lane & 1) == 0;
  float bgv[4];
#pragma unroll
  for (int ni = 0; ni < 4; ++ni) bgv[ni] = bg[nt * 128 + wc * 64 + ni * 16 + c];
  int bt = m0 >> 8;
  bool eblk = ((m0 & 255) == 0) && (wr == 0) && (q == 0);
  u16* obase = outp + (size_t)m0 * 256;
#pragma unroll
  for (int mi = 0; mi < 4; ++mi) {
    int row0 = wr * 64 + mi * 16 + q * 4;
#pragma unroll
    for (int ni = 0; ni < 4; ++ni) {
      float raw[4], v[4];
#pragma unroll
      for (int r = 0; r < 4; ++r) { raw[r] = acc[mi][ni][r]; v[r] = raw[r] + bgv[ni]; }
      int colb = nt * 128 + wc * 64 + ni * 16 + (c & ~1);
      store_pairs(obase, row0, 256, colb, v, ev);
      if (eblk && mi == 0) {
        store_pairs_f32(edge + (size_t)bt * 1024, 0, 256, colb, raw, ev);
      }
    }
  }
}

// ---- fixup: overwrite p<4 nodes with GCN aggregation (closed-form dinv) ----
__device__ __forceinline__ float dinv0(int t) {
  if (t == 0) return 0.44721359549995793f;   // 1/sqrt(5)
  if (t == 127) return 0.7071067811865476f;  // 1/sqrt(2)
  return 0.4082482904638631f;                // 1/sqrt(6)
}
__global__ __launch_bounds__(256) void k_fix(const float* __restrict__ edge, const float* __restrict__ bg,
                                             u16* __restrict__ outp) {
  int bt = blockIdx.x;
  int t = bt & 127;
  int j = threadIdx.x;
  const float ISQ2 = 0.7071067811865476f;
  float bgv = bg[j];
  float e_t = edge[(size_t)bt * 1024 + j];
  float At = dinv0(t);
  float o0 = bgv + At * At * e_t;
  if (t <= 126) {
    float At1 = dinv0(t + 1);
    const float* en = edge + (size_t)(bt + 1) * 1024;
    float s = At1 * en[j] + ISQ2 * (en[256 + j] + en[512 + j] + en[768 + j]);
    o0 += At * s;
  }
  float em1 = 0.f, Atm1 = 0.f;
  if (t >= 1) {
    Atm1 = dinv0(t - 1);
    em1 = edge[(size_t)(bt - 1) * 1024 + j];
    o0 += At * Atm1 * em1;
  }
  u16* ob = outp + (size_t)bt * 65536;
  ob[j] = f2b(o0);
#pragma unroll
  for (int k = 1; k <= 3; ++k) {
    float m = edge[(size_t)bt * 1024 + k * 256 + j];
    float ok = (t == 0) ? (bgv + m) : (bgv + 0.5f * m + ISQ2 * Atm1 * em1);
    ob[k * 256 + j] = f2b(ok);
  }
}

// ---- G3: y[bt][co][p] = tconv2(out)*s2 + t2  (m=co, n=p), fp32 out ----
__global__ __launch_bounds__(256) void k_g3(const u16* __restrict__ outp, const u16* __restrict__ Wup,
                                            const float* __restrict__ s2, const float* __restrict__ t2,
                                            float* __restrict__ y) {
  __shared__ u16 sA[128 * 32];
  __shared__ u16 sB[128 * 32];
  __shared__ float ss2[128], st2[128];
  int blk = blockIdx.x;
  int bt = blk >> 2;
  int tile = blk & 3;
  int tm = tile >> 1, tn = tile & 1;
  int t = bt & 127;
  int tid = threadIdx.x, lane = tid & 63, w = tid >> 6;
  int wr = w >> 1, wc = w & 1;
  if (tid < 128) {
    int co = tm * 128 + tid;
    ss2[tid] = s2[co];
    st2[tid] = t2[co];
  }
  f32x4 acc[4][4];
#pragma unroll
  for (int i = 0; i < 4; ++i)
#pragma unroll
    for (int j = 0; j < 4; ++j) acc[i][j] = (f32x4){0.f, 0.f, 0.f, 0.f};

#pragma unroll
  for (int kk = 0; kk < 3; ++kk) {
    int tp = t - 1 + kk;
    if (tp < 0 || tp > 127) continue;
    const u16* gA = Wup + (size_t)kk * 65536 + (tm * 128) * 256;
    const u16* gB = outp + ((size_t)(bt - t + tp) * 256 + tn * 128) * 256;
    for (int ks = 0; ks < 8; ++ks) {
      stage_tile(gA + ks * 32, 256, sA, w, lane);
      stage_tile(gB + ks * 32, 256, sB, w, lane);
      __syncthreads();
      mfma_tiles(sA, sB, acc, wr, wc, lane);
      __syncthreads();
    }
  }
  int q = lane >> 4, c = lane & 15;
  bool ev = (lane & 1) == 0;
  float* ybase = y + (size_t)bt * 65536;
#pragma unroll
  for (int mi = 0; mi < 4; ++mi) {
    int rl = wr * 64 + mi * 16 + q * 4;
    float sv[4], tv[4];
#pragma unroll
    for (int r = 0; r < 4; ++r) { sv[r] = ss2[rl + r]; tv[r] = st2[rl + r]; }
#pragma unroll
    for (int ni = 0; ni < 4; ++ni) {
      float v[4];
#pragma unroll
      for (int r = 0; r < 4; ++r) v[r] = acc[mi][ni][r] * sv[r] + tv[r];
      int colb = tn * 128 + wc * 64 + ni * 16 + (c & ~1);
      store_pairs_f32(ybase, tm * 128 + rl, 256, colb, v, ev);
    }
  }
}

extern "C" void kernel_launch(void* const* d_in, const int* in_sizes, int n_in,
                              void* d_out, int out_size, void* d_ws, size_t ws_size,
                              hipStream_t stream) {
  (void)in_sizes; (void)n_in; (void)out_size; (void)ws_size;
  const float* x  = (const float*)d_in[0];
  const float* Wd = (const float*)d_in[2];
  const float* s1 = (const float*)d_in[3];
  const float* t1 = (const float*)d_in[4];
  const float* Wg = (const float*)d_in[5];
  const float* bg = (const float*)d_in[6];
  const float* Wu = (const float*)d_in[7];
  const float* s2 = (const float*)d_in[8];
  const float* t2 = (const float*)d_in[9];
  float* y = (float*)d_out;
  char* ws = (char*)d_ws;
  u16*   xT    = (u16*)(ws);                    // 64 MiB (bf16), reused as out_pre
  u16*   nodes = (u16*)(ws + 67108864);         // 64 MiB (bf16)
  float* edge  = (float*)(ws + 134217728);      // 2 MiB (fp32)
  u16*   Wdp   = (u16*)(ws + 136314880);        // 384 KiB
  u16*   Wup   = (u16*)(ws + 136708096);        // 384 KiB
  u16*   WgT   = (u16*)(ws + 137101312);        // 128 KiB
  u16*   outp  = xT;

  k_pack<<<dim3(1024), dim3(256), 0, stream>>>(Wd, Wg, Wu, Wdp, WgT, Wup);
  k_transpose<<<dim3(8192), dim3(256), 0, stream>>>(x, xT);
  k_g1<<<dim3(2048), dim3(256), 0, stream>>>(xT, Wdp, s1, t1, nodes);
  k_g2<<<dim3(2048), dim3(256), 0, stream>>>(nodes, WgT, bg, outp, edge);
  k_fix<<<dim3(512), dim3(256), 0, stream>>>(edge, bg, outp);
  k_g3<<<dim3(2048), dim3(256), 0, stream>>>(outp, Wup, s2, t2, y);
}

// Round 3
// 429.211 us; speedup vs baseline: 1.0902x; 1.0902x over previous
//
#include <hip/hip_runtime.h>

typedef __attribute__((ext_vector_type(8))) short short8;
typedef __attribute__((ext_vector_type(4))) float f32x4;
typedef unsigned short u16;
typedef unsigned int u32;

__device__ __forceinline__ void gld_lds16(const void* g, void* l) {
  __builtin_amdgcn_global_load_lds((const __attribute__((address_space(1))) void*)g,
                                   (__attribute__((address_space(3))) void*)l,
                                   16, 0, 0);
}

__device__ __forceinline__ u16 f2b(float x) {
  union { float f; u32 u; } v; v.f = x;
  u32 u = v.u;
  return (u16)((u + 0x7FFFu + ((u >> 16) & 1u)) >> 16);
}
__device__ __forceinline__ float b2f(u16 x) {
  union { u32 u; float f; } v; v.u = ((u32)x) << 16; return v.f;
}
__device__ __forceinline__ u32 pack_pair(float lo, float hi) {
  return (u32)f2b(lo) | ((u32)f2b(hi) << 16);
}

// ---- prep: WdT[kk][ci][co], Wup[kk][co][ci], WgS[j][co]=Wg^T*s1 (bf16); c0/tWg (fp32) ----
__global__ __launch_bounds__(256) void k_prep(const float* __restrict__ Wd, const float* __restrict__ Wg,
                                              const float* __restrict__ Wu,
                                              const float* __restrict__ s1, const float* __restrict__ t1,
                                              const float* __restrict__ bg,
                                              u16* __restrict__ WdT, u16* __restrict__ Wup,
                                              u16* __restrict__ WgS,
                                              float* __restrict__ c0, float* __restrict__ tWg) {
  int blk = blockIdx.x;
  int tid = threadIdx.x;
  if (blk == 1024) {  // c0[j] = t1 @ Wg[:,j] + bg[j]
    int j = tid;
    float a = 0.f;
    for (int co = 0; co < 256; ++co) a += t1[co] * Wg[co * 256 + j];
    tWg[j] = a;
    c0[j] = a + bg[j];
    return;
  }
  int id = blk * 256 + tid;
  if (id < 196608) {
    int kk = id >> 16;
    int rem = id & 65535;
    int a = rem >> 8, b = rem & 255;
    // Wup[kk][co=a][ci=b]
    Wup[id] = f2b(Wu[(u32)a * 768 + (u32)b * 3 + kk]);
    // WdT[kk][ci=a][co=b]
    WdT[id] = f2b(Wd[(u32)b * 768 + (u32)a * 3 + kk]);
  } else {
    int id2 = id - 196608;
    int j = id2 >> 8, co = id2 & 255;
    WgS[id2] = f2b(Wg[co * 256 + j] * s1[co]);
  }
}

// ---- transpose+cast x[tl][ci][p] (fp32) -> xT[tl][p][ci] (bf16) ----
__global__ __launch_bounds__(256) void k_transpose(const float* __restrict__ x, u16* __restrict__ xT) {
  __shared__ u16 tile[64][72];
  int blk = blockIdx.x;
  int tl = blk >> 4;
  int sub = blk & 15;
  int ci0 = (sub >> 2) << 6;
  int p0 = (sub & 3) << 6;
  int tid = threadIdx.x;
  int i = tid >> 2;
  int ch = tid & 3;
  const float* gsrc = x + (size_t)tl * 65536 + (ci0 + i) * 256 + p0 + ch * 16;
  __align__(16) u16 cv[16];
#pragma unroll
  for (int v4 = 0; v4 < 4; ++v4) {
    float4 f = *(const float4*)(gsrc + v4 * 4);
    cv[v4 * 4 + 0] = f2b(f.x);
    cv[v4 * 4 + 1] = f2b(f.y);
    cv[v4 * 4 + 2] = f2b(f.z);
    cv[v4 * 4 + 3] = f2b(f.w);
  }
  *(uint4*)&tile[i][ch * 16] = *(const uint4*)&cv[0];
  *(uint4*)&tile[i][ch * 16 + 8] = *(const uint4*)&cv[8];
  __syncthreads();
  __align__(16) u16 tmp[16];
#pragma unroll
  for (int cc = 0; cc < 16; ++cc) tmp[cc] = tile[ch * 16 + cc][i];
  u16* gdst = xT + (size_t)tl * 65536 + (p0 + i) * 256 + ci0 + ch * 16;
  *(uint4*)(gdst) = *(const uint4*)&tmp[0];
  *(uint4*)(gdst + 8) = *(const uint4*)&tmp[8];
}

// ---------------- GEMM building blocks ----------------
__device__ __forceinline__ void stage_tile(const u16* __restrict__ g, int ldg, u16* s, int w, int lane) {
  int r = lane >> 2;
  int cc = (lane & 3) * 8;
#pragma unroll
  for (int j = 0; j < 2; ++j) {
    gld_lds16(g + (w * 32 + j * 16 + r) * ldg + cc, s + (w * 32 + j * 16) * 32);
  }
}

__device__ __forceinline__ void mfma_tiles(const u16* sA, const u16* sB, f32x4 acc[4][4],
                                           int wr, int wc, int lane) {
  int m16 = lane & 15;
  int q8 = (lane >> 4) * 8;
  short8 a[4], b[4];
#pragma unroll
  for (int mi = 0; mi < 4; ++mi) a[mi] = *(const short8*)(sA + (wr * 64 + mi * 16 + m16) * 32 + q8);
#pragma unroll
  for (int ni = 0; ni < 4; ++ni) b[ni] = *(const short8*)(sB + (wc * 64 + ni * 16 + m16) * 32 + q8);
#pragma unroll
  for (int mi = 0; mi < 4; ++mi)
#pragma unroll
    for (int ni = 0; ni < 4; ++ni)
      acc[mi][ni] = __builtin_amdgcn_mfma_f32_16x16x32_bf16(a[mi], b[ni], acc[mi][ni], 0, 0, 0);
}

__device__ __forceinline__ void store_pairs(u16* base, int row0, int stride, int colb,
                                            const float v[4], bool ev) {
  float pv[4];
#pragma unroll
  for (int r = 0; r < 4; ++r) pv[r] = __shfl_xor(v[r], 1, 64);
  u32 wd0 = ev ? pack_pair(v[0], pv[0]) : pack_pair(pv[0], v[0]);
  u32 wd1 = ev ? pack_pair(v[1], pv[1]) : pack_pair(pv[1], v[1]);
  u32 wd2 = ev ? pack_pair(v[2], pv[2]) : pack_pair(pv[2], v[2]);
  u32 wd3 = ev ? pack_pair(v[3], pv[3]) : pack_pair(pv[3], v[3]);
  u32 wa = ev ? wd0 : wd2;
  u32 wb = ev ? wd1 : wd3;
  int rs = ev ? 0 : 2;
  *(u32*)(base + (size_t)(row0 + rs) * stride + colb) = wa;
  *(u32*)(base + (size_t)(row0 + rs + 1) * stride + colb) = wb;
}

__device__ __forceinline__ void store_pairs_f32(float* base, int row0, int stride, int colb,
                                                const float v[4], bool ev) {
  float pv[4];
#pragma unroll
  for (int r = 0; r < 4; ++r) pv[r] = __shfl_xor(v[r], 1, 64);
  float2 wa, wb;
  if (ev) { wa = make_float2(v[0], pv[0]); wb = make_float2(v[1], pv[1]); }
  else    { wa = make_float2(pv[2], v[2]); wb = make_float2(pv[3], v[3]); }
  int rs = ev ? 0 : 2;
  *(float2*)(base + (size_t)(row0 + rs) * stride + colb) = wa;
  *(float2*)(base + (size_t)(row0 + rs + 1) * stride + colb) = wb;
}

// ---- wcomb: Wcomb[kk][j][ci] = sum_co WgS[j][co] * WdT[kk][ci][co]  (12 blocks) ----
__global__ __launch_bounds__(256) void k_wcomb(const u16* __restrict__ WgS, const u16* __restrict__ WdT,
                                               u16* __restrict__ Wcomb) {
  __shared__ u16 sA[128 * 32];
  __shared__ u16 sB[128 * 32];
  int blk = blockIdx.x;
  int kk = blk >> 2;
  int tile = blk & 3;
  int tm = tile >> 1, tn = tile & 1;
  int tid = threadIdx.x, lane = tid & 63, w = tid >> 6;
  int wr = w >> 1, wc = w & 1;
  f32x4 acc[4][4];
#pragma unroll
  for (int i = 0; i < 4; ++i)
#pragma unroll
    for (int j = 0; j < 4; ++j) acc[i][j] = (f32x4){0.f, 0.f, 0.f, 0.f};
  const u16* gA = WgS + (size_t)(tm * 128) * 256;
  const u16* gB = WdT + (size_t)kk * 65536 + (size_t)(tn * 128) * 256;
  for (int ks = 0; ks < 8; ++ks) {
    stage_tile(gA + ks * 32, 256, sA, w, lane);
    stage_tile(gB + ks * 32, 256, sB, w, lane);
    __syncthreads();
    mfma_tiles(sA, sB, acc, wr, wc, lane);
    __syncthreads();
  }
  int q = lane >> 4, c = lane & 15;
  bool ev = (lane & 1) == 0;
  u16* obase = Wcomb + (size_t)kk * 65536;
#pragma unroll
  for (int mi = 0; mi < 4; ++mi) {
    int row0 = tm * 128 + wr * 64 + mi * 16 + q * 4;
#pragma unroll
    for (int ni = 0; ni < 4; ++ni) {
      float v[4];
#pragma unroll
      for (int r = 0; r < 4; ++r) v[r] = acc[mi][ni][r];
      int colb = tn * 128 + wc * 64 + ni * 16 + (c & ~1);
      store_pairs(obase, row0, 256, colb, v, ev);
    }
  }
}

// ---- G12: out_pre[bt][p][j] = sum_kk xT_shift @ Wcomb_kk^T + c0 ; edge dump for p<4 ----
__global__ __launch_bounds__(256) void k_g12(const u16* __restrict__ xT, const u16* __restrict__ Wcomb,
                                             const float* __restrict__ c0, const float* __restrict__ tWg,
                                             u16* __restrict__ outp, float* __restrict__ edge) {
  __shared__ u16 sA[128 * 64];
  __shared__ u16 sB[128 * 64];
  int blk = blockIdx.x;
  int bt = blk >> 2;
  int tile = blk & 3;
  int tm = tile >> 1, tn = tile & 1;
  int t = bt & 127;
  int tid = threadIdx.x, lane = tid & 63, w = tid >> 6;
  int wr = w >> 1, wc = w & 1;
  f32x4 acc[4][4];
#pragma unroll
  for (int i = 0; i < 4; ++i)
#pragma unroll
    for (int j = 0; j < 4; ++j) acc[i][j] = (f32x4){0.f, 0.f, 0.f, 0.f};

#pragma unroll
  for (int kk = 0; kk < 3; ++kk) {
    int tp = t - 1 + kk;
    if (tp < 0 || tp > 127) continue;
    const u16* gA = xT + ((size_t)(bt - t + tp) * 256 + tm * 128) * 256;
    const u16* gB = Wcomb + (size_t)kk * 65536 + (size_t)(tn * 128) * 256;
    for (int ks = 0; ks < 4; ++ks) {  // BK=64: two 32-chunks per barrier pair
      stage_tile(gA + ks * 64, 256, sA, w, lane);
      stage_tile(gA + ks * 64 + 32, 256, sA + 4096, w, lane);
      stage_tile(gB + ks * 64, 256, sB, w, lane);
      stage_tile(gB + ks * 64 + 32, 256, sB + 4096, w, lane);
      __syncthreads();
      mfma_tiles(sA, sB, acc, wr, wc, lane);
      mfma_tiles(sA + 4096, sB + 4096, acc, wr, wc, lane);
      __syncthreads();
    }
  }
  int q = lane >> 4, c = lane & 15;
  bool ev = (lane & 1) == 0;
  float c0v[4], tWgv[4];
#pragma unroll
  for (int ni = 0; ni < 4; ++ni) {
    int j = tn * 128 + wc * 64 + ni * 16 + c;
    c0v[ni] = c0[j];
    tWgv[ni] = tWg[j];
  }
  bool eblk = (tm == 0) && (wr == 0) && (q == 0);
  u16* obase = outp + (size_t)bt * 65536;
#pragma unroll
  for (int mi = 0; mi < 4; ++mi) {
    int row0 = tm * 128 + wr * 64 + mi * 16 + q * 4;
#pragma unroll
    for (int ni = 0; ni < 4; ++ni) {
      float v[4];
#pragma unroll
      for (int r = 0; r < 4; ++r) v[r] = acc[mi][ni][r] + c0v[ni];
      int colb = tn * 128 + wc * 64 + ni * 16 + (c & ~1);
      store_pairs(obase, row0, 256, colb, v, ev);
      if (eblk && mi == 0) {
        float vE[4];
#pragma unroll
        for (int r = 0; r < 4; ++r) vE[r] = acc[0][ni][r] + tWgv[ni];
        store_pairs_f32(edge + (size_t)bt * 1024, 0, 256, colb, vE, ev);
      }
    }
  }
}

// ---- fixup: overwrite p<4 nodes with GCN aggregation (closed-form dinv) ----
__device__ __forceinline__ float dinv0(int t) {
  if (t == 0) return 0.44721359549995793f;   // 1/sqrt(5)
  if (t == 127) return 0.7071067811865476f;  // 1/sqrt(2)
  return 0.4082482904638631f;                // 1/sqrt(6)
}
__global__ __launch_bounds__(256) void k_fix(const float* __restrict__ edge, const float* __restrict__ bg,
                                             u16* __restrict__ outp) {
  int bt = blockIdx.x;
  int t = bt & 127;
  int j = threadIdx.x;
  const float ISQ2 = 0.7071067811865476f;
  float bgv = bg[j];
  float e_t = edge[(size_t)bt * 1024 + j];
  float At = dinv0(t);
  float o0 = bgv + At * At * e_t;
  if (t <= 126) {
    float At1 = dinv0(t + 1);
    const float* en = edge + (size_t)(bt + 1) * 1024;
    float s = At1 * en[j] + ISQ2 * (en[256 + j] + en[512 + j] + en[768 + j]);
    o0 += At * s;
  }
  float em1 = 0.f, Atm1 = 0.f;
  if (t >= 1) {
    Atm1 = dinv0(t - 1);
    em1 = edge[(size_t)(bt - 1) * 1024 + j];
    o0 += At * Atm1 * em1;
  }
  u16* ob = outp + (size_t)bt * 65536;
  ob[j] = f2b(o0);
#pragma unroll
  for (int k = 1; k <= 3; ++k) {
    float m = edge[(size_t)bt * 1024 + k * 256 + j];
    float ok = (t == 0) ? (bgv + m) : (bgv + 0.5f * m + ISQ2 * Atm1 * em1);
    ob[k * 256 + j] = f2b(ok);
  }
}

// ---- G3: y[bt][co][p] = tconv2(out)*s2 + t2  (m=co, n=p), fp32 out ----
__global__ __launch_bounds__(256) void k_g3(const u16* __restrict__ outp, const u16* __restrict__ Wup,
                                            const float* __restrict__ s2, const float* __restrict__ t2,
                                            float* __restrict__ y) {
  __shared__ u16 sA[128 * 64];
  __shared__ u16 sB[128 * 64];
  __shared__ float ss2[128], st2[128];
  int blk = blockIdx.x;
  int bt = blk >> 2;
  int tile = blk & 3;
  int tm = tile >> 1, tn = tile & 1;
  int t = bt & 127;
  int tid = threadIdx.x, lane = tid & 63, w = tid >> 6;
  int wr = w >> 1, wc = w & 1;
  if (tid < 128) {
    int co = tm * 128 + tid;
    ss2[tid] = s2[co];
    st2[tid] = t2[co];
  }
  f32x4 acc[4][4];
#pragma unroll
  for (int i = 0; i < 4; ++i)
#pragma unroll
    for (int j = 0; j < 4; ++j) acc[i][j] = (f32x4){0.f, 0.f, 0.f, 0.f};

#pragma unroll
  for (int kk = 0; kk < 3; ++kk) {
    int tp = t - 1 + kk;
    if (tp < 0 || tp > 127) continue;
    const u16* gA = Wup + (size_t)kk * 65536 + (size_t)(tm * 128) * 256;
    const u16* gB = outp + ((size_t)(bt - t + tp) * 256 + tn * 128) * 256;
    for (int ks = 0; ks < 4; ++ks) {  // BK=64
      stage_tile(gA + ks * 64, 256, sA, w, lane);
      stage_tile(gA + ks * 64 + 32, 256, sA + 4096, w, lane);
      stage_tile(gB + ks * 64, 256, sB, w, lane);
      stage_tile(gB + ks * 64 + 32, 256, sB + 4096, w, lane);
      __syncthreads();
      mfma_tiles(sA, sB, acc, wr, wc, lane);
      mfma_tiles(sA + 4096, sB + 4096, acc, wr, wc, lane);
      __syncthreads();
    }
  }
  int q = lane >> 4, c = lane & 15;
  bool ev = (lane & 1) == 0;
  float* ybase = y + (size_t)bt * 65536;
#pragma unroll
  for (int mi = 0; mi < 4; ++mi) {
    int rl = wr * 64 + mi * 16 + q * 4;
    float sv[4], tv[4];
#pragma unroll
    for (int r = 0; r < 4; ++r) { sv[r] = ss2[rl + r]; tv[r] = st2[rl + r]; }
#pragma unroll
    for (int ni = 0; ni < 4; ++ni) {
      float v[4];
#pragma unroll
      for (int r = 0; r < 4; ++r) v[r] = acc[mi][ni][r] * sv[r] + tv[r];
      int colb = tn * 128 + wc * 64 + ni * 16 + (c & ~1);
      store_pairs_f32(ybase, tm * 128 + rl, 256, colb, v, ev);
    }
  }
}

extern "C" void kernel_launch(void* const* d_in, const int* in_sizes, int n_in,
                              void* d_out, int out_size, void* d_ws, size_t ws_size,
                              hipStream_t stream) {
  (void)in_sizes; (void)n_in; (void)out_size; (void)ws_size;
  const float* x  = (const float*)d_in[0];
  const float* Wd = (const float*)d_in[2];
  const float* s1 = (const float*)d_in[3];
  const float* t1 = (const float*)d_in[4];
  const float* Wg = (const float*)d_in[5];
  const float* bg = (const float*)d_in[6];
  const float* Wu = (const float*)d_in[7];
  const float* s2 = (const float*)d_in[8];
  const float* t2 = (const float*)d_in[9];
  float* y = (float*)d_out;
  char* ws = (char*)d_ws;
  u16*   outp  = (u16*)(ws);                    // 64 MiB bf16
  u16*   xT    = (u16*)(ws + 67108864);         // 64 MiB bf16
  // region [128 MiB, ...): edge (2 MiB, written at g12) overlays WdT/WgS (dead after wcomb)
  float* edge  = (float*)(ws + 134217728);      // 2 MiB fp32
  u16*   WdT   = (u16*)(ws + 134217728);        // 384 KiB (dead after k_wcomb)
  u16*   WgS   = (u16*)(ws + 134611072);        // 128 KiB (dead after k_wcomb)
  u16*   Wup   = (u16*)(ws + 136314880);        // 384 KiB (live through g3)
  u16*   Wcomb = (u16*)(ws + 136708096);        // 384 KiB (live through g12)
  float* c0    = (float*)(ws + 137101312);      // 1 KiB
  float* tWg   = (float*)(ws + 137102336);      // 1 KiB

  k_prep<<<dim3(1025), dim3(256), 0, stream>>>(Wd, Wg, Wu, s1, t1, bg, WdT, Wup, WgS, c0, tWg);
  k_wcomb<<<dim3(12), dim3(256), 0, stream>>>(WgS, WdT, Wcomb);
  k_transpose<<<dim3(8192), dim3(256), 0, stream>>>(x, xT);
  k_g12<<<dim3(2048), dim3(256), 0, stream>>>(xT, Wcomb, c0, tWg, outp, edge);
  k_fix<<<dim3(512), dim3(256), 0, stream>>>(edge, bg, outp);
  k_g3<<<dim3(2048), dim3(256), 0, stream>>>(outp, Wup, s2, t2, y);
}

// Round 4
// 421.484 us; speedup vs baseline: 1.1102x; 1.0183x over previous
//
#include <hip/hip_runtime.h>

typedef __attribute__((ext_vector_type(8))) short short8;
typedef __attribute__((ext_vector_type(4))) float f32x4;
typedef unsigned short u16;
typedef unsigned int u32;

__device__ __forceinline__ void gld_lds16(const void* g, void* l) {
  __builtin_amdgcn_global_load_lds((const __attribute__((address_space(1))) void*)g,
                                   (__attribute__((address_space(3))) void*)l,
                                   16, 0, 0);
}

__device__ __forceinline__ u16 f2b(float x) {
  union { float f; u32 u; } v; v.f = x;
  u32 u = v.u;
  return (u16)((u + 0x7FFFu + ((u >> 16) & 1u)) >> 16);
}
__device__ __forceinline__ float b2f(u16 x) {
  union { u32 u; float f; } v; v.u = ((u32)x) << 16; return v.f;
}
__device__ __forceinline__ u32 pack_pair(float lo, float hi) {
  return (u32)f2b(lo) | ((u32)f2b(hi) << 16);
}

// ---- prep: WdT[kk][ci][co], Wup[kk][co][ci], WgS[j][co]=Wg^T*s1 (bf16); c0/tWg (fp32) ----
__global__ __launch_bounds__(256) void k_prep(const float* __restrict__ Wd, const float* __restrict__ Wg,
                                              const float* __restrict__ Wu,
                                              const float* __restrict__ s1, const float* __restrict__ t1,
                                              const float* __restrict__ bg,
                                              u16* __restrict__ WdT, u16* __restrict__ Wup,
                                              u16* __restrict__ WgS,
                                              float* __restrict__ c0, float* __restrict__ tWg) {
  int blk = blockIdx.x;
  int tid = threadIdx.x;
  if (blk == 1024) {  // c0[j] = t1 @ Wg[:,j] + bg[j]
    int j = tid;
    float a = 0.f;
    for (int co = 0; co < 256; ++co) a += t1[co] * Wg[co * 256 + j];
    tWg[j] = a;
    c0[j] = a + bg[j];
    return;
  }
  int id = blk * 256 + tid;
  if (id < 196608) {
    int kk = id >> 16;
    int rem = id & 65535;
    int a = rem >> 8, b = rem & 255;
    Wup[id] = f2b(Wu[(u32)a * 768 + (u32)b * 3 + kk]);   // Wup[kk][co=a][ci=b]
    WdT[id] = f2b(Wd[(u32)b * 768 + (u32)a * 3 + kk]);   // WdT[kk][ci=a][co=b]
  } else {
    int id2 = id - 196608;
    int j = id2 >> 8, co = id2 & 255;
    WgS[id2] = f2b(Wg[co * 256 + j] * s1[co]);
  }
}

// ---- transpose+cast x[tl][ci][p] (fp32) -> xT[tl][p][ci] (bf16) ----
__global__ __launch_bounds__(256) void k_transpose(const float* __restrict__ x, u16* __restrict__ xT) {
  __shared__ u16 tile[64][72];
  int blk = blockIdx.x;
  int tl = blk >> 4;
  int sub = blk & 15;
  int ci0 = (sub >> 2) << 6;
  int p0 = (sub & 3) << 6;
  int tid = threadIdx.x;
  int i = tid >> 2;
  int ch = tid & 3;
  const float* gsrc = x + (size_t)tl * 65536 + (ci0 + i) * 256 + p0 + ch * 16;
  __align__(16) u16 cv[16];
#pragma unroll
  for (int v4 = 0; v4 < 4; ++v4) {
    float4 f = *(const float4*)(gsrc + v4 * 4);
    cv[v4 * 4 + 0] = f2b(f.x);
    cv[v4 * 4 + 1] = f2b(f.y);
    cv[v4 * 4 + 2] = f2b(f.z);
    cv[v4 * 4 + 3] = f2b(f.w);
  }
  *(uint4*)&tile[i][ch * 16] = *(const uint4*)&cv[0];
  *(uint4*)&tile[i][ch * 16 + 8] = *(const uint4*)&cv[8];
  __syncthreads();
  __align__(16) u16 tmp[16];
#pragma unroll
  for (int cc = 0; cc < 16; ++cc) tmp[cc] = tile[ch * 16 + cc][i];
  u16* gdst = xT + (size_t)tl * 65536 + (p0 + i) * 256 + ci0 + ch * 16;
  *(uint4*)(gdst) = *(const uint4*)&tmp[0];
  *(uint4*)(gdst + 8) = *(const uint4*)&tmp[8];
}

// ---------------- GEMM building blocks ----------------
__device__ __forceinline__ void stage_tile(const u16* __restrict__ g, int ldg, u16* s, int w, int lane) {
  int r = lane >> 2;
  int cc = (lane & 3) * 8;
#pragma unroll
  for (int j = 0; j < 2; ++j) {
    gld_lds16(g + (w * 32 + j * 16 + r) * ldg + cc, s + (w * 32 + j * 16) * 32);
  }
}

__device__ __forceinline__ void mfma_tiles(const u16* sA, const u16* sB, f32x4 acc[4][4],
                                           int wr, int wc, int lane) {
  int m16 = lane & 15;
  int q8 = (lane >> 4) * 8;
  short8 a[4], b[4];
#pragma unroll
  for (int mi = 0; mi < 4; ++mi) a[mi] = *(const short8*)(sA + (wr * 64 + mi * 16 + m16) * 32 + q8);
#pragma unroll
  for (int ni = 0; ni < 4; ++ni) b[ni] = *(const short8*)(sB + (wc * 64 + ni * 16 + m16) * 32 + q8);
#pragma unroll
  for (int mi = 0; mi < 4; ++mi)
#pragma unroll
    for (int ni = 0; ni < 4; ++ni)
      acc[mi][ni] = __builtin_amdgcn_mfma_f32_16x16x32_bf16(a[mi], b[ni], acc[mi][ni], 0, 0, 0);
}

__device__ __forceinline__ void store_pairs(u16* base, int row0, int stride, int colb,
                                            const float v[4], bool ev) {
  float pv[4];
#pragma unroll
  for (int r = 0; r < 4; ++r) pv[r] = __shfl_xor(v[r], 1, 64);
  u32 wd0 = ev ? pack_pair(v[0], pv[0]) : pack_pair(pv[0], v[0]);
  u32 wd1 = ev ? pack_pair(v[1], pv[1]) : pack_pair(pv[1], v[1]);
  u32 wd2 = ev ? pack_pair(v[2], pv[2]) : pack_pair(pv[2], v[2]);
  u32 wd3 = ev ? pack_pair(v[3], pv[3]) : pack_pair(pv[3], v[3]);
  u32 wa = ev ? wd0 : wd2;
  u32 wb = ev ? wd1 : wd3;
  int rs = ev ? 0 : 2;
  *(u32*)(base + (size_t)(row0 + rs) * stride + colb) = wa;
  *(u32*)(base + (size_t)(row0 + rs + 1) * stride + colb) = wb;
}

__device__ __forceinline__ void store_pairs_f32(float* base, int row0, int stride, int colb,
                                                const float v[4], bool ev) {
  float pv[4];
#pragma unroll
  for (int r = 0; r < 4; ++r) pv[r] = __shfl_xor(v[r], 1, 64);
  float2 wa, wb;
  if (ev) { wa = make_float2(v[0], pv[0]); wb = make_float2(v[1], pv[1]); }
  else    { wa = make_float2(pv[2], v[2]); wb = make_float2(pv[3], v[3]); }
  int rs = ev ? 0 : 2;
  *(float2*)(base + (size_t)(row0 + rs) * stride + colb) = wa;
  *(float2*)(base + (size_t)(row0 + rs + 1) * stride + colb) = wb;
}

// ---- wcomb: Wcomb[kk][j][ci] = sum_co WgS[j][co] * WdT[kk][ci][co]  (12 blocks) ----
__global__ __launch_bounds__(256) void k_wcomb(const u16* __restrict__ WgS, const u16* __restrict__ WdT,
                                               u16* __restrict__ Wcomb) {
  __shared__ u16 sA[128 * 32];
  __shared__ u16 sB[128 * 32];
  int blk = blockIdx.x;
  int kk = blk >> 2;
  int tile = blk & 3;
  int tm = tile >> 1, tn = tile & 1;
  int tid = threadIdx.x, lane = tid & 63, w = tid >> 6;
  int wr = w >> 1, wc = w & 1;
  f32x4 acc[4][4];
#pragma unroll
  for (int i = 0; i < 4; ++i)
#pragma unroll
    for (int j = 0; j < 4; ++j) acc[i][j] = (f32x4){0.f, 0.f, 0.f, 0.f};
  const u16* gA = WgS + (size_t)(tm * 128) * 256;
  const u16* gB = WdT + (size_t)kk * 65536 + (size_t)(tn * 128) * 256;
  for (int ks = 0; ks < 8; ++ks) {
    stage_tile(gA + ks * 32, 256, sA, w, lane);
    stage_tile(gB + ks * 32, 256, sB, w, lane);
    __syncthreads();
    mfma_tiles(sA, sB, acc, wr, wc, lane);
    __syncthreads();
  }
  int q = lane >> 4, c = lane & 15;
  bool ev = (lane & 1) == 0;
  u16* obase = Wcomb + (size_t)kk * 65536;
#pragma unroll
  for (int mi = 0; mi < 4; ++mi) {
    int row0 = tm * 128 + wr * 64 + mi * 16 + q * 4;
#pragma unroll
    for (int ni = 0; ni < 4; ++ni) {
      float v[4];
#pragma unroll
      for (int r = 0; r < 4; ++r) v[r] = acc[mi][ni][r];
      int colb = tn * 128 + wc * 64 + ni * 16 + (c & ~1);
      store_pairs(obase, row0, 256, colb, v, ev);
    }
  }
}

// ---- G12: out_pre[bt][p][j] = sum_kk xT_shift @ Wcomb_kk^T + c0 ; edge dump for p<4 ----
// ping-pong double-buffer, 1 barrier/chunk; XCD swizzle for L2 frame reuse
__global__ __launch_bounds__(256) void k_g12(const u16* __restrict__ xT, const u16* __restrict__ Wcomb,
                                             const float* __restrict__ c0, const float* __restrict__ tWg,
                                             u16* __restrict__ outp, float* __restrict__ edge) {
  __shared__ u16 sA[2][128 * 32];
  __shared__ u16 sB[2][128 * 32];
  int b = blockIdx.x;
  int logical = (b & 7) * 256 + (b >> 3);   // XCD k gets bt range [64k, 64k+64)
  int bt = logical >> 2;
  int tile = logical & 3;
  int tm = tile >> 1, tn = tile & 1;
  int t = bt & 127;
  int tid = threadIdx.x, lane = tid & 63, w = tid >> 6;
  int wr = w >> 1, wc = w & 1;
  f32x4 acc[4][4];
#pragma unroll
  for (int i = 0; i < 4; ++i)
#pragma unroll
    for (int j = 0; j < 4; ++j) acc[i][j] = (f32x4){0.f, 0.f, 0.f, 0.f};

  const u16* Ap[3];
  const u16* Bp[3];
  int nf = 0;
#pragma unroll
  for (int kk = 0; kk < 3; ++kk) {
    int tp = t - 1 + kk;
    if (tp < 0 || tp > 127) continue;
    Ap[nf] = xT + ((size_t)(bt - t + tp) * 256 + tm * 128) * 256;
    Bp[nf] = Wcomb + (size_t)kk * 65536 + (size_t)(tn * 128) * 256;
    ++nf;
  }
  int nc = nf * 8;
  stage_tile(Ap[0], 256, sA[0], w, lane);
  stage_tile(Bp[0], 256, sB[0], w, lane);
  __syncthreads();
  for (int c = 0; c < nc; ++c) {
    int nx = c + 1;
    if (nx < nc) {
      stage_tile(Ap[nx >> 3] + (nx & 7) * 32, 256, sA[nx & 1], w, lane);
      stage_tile(Bp[nx >> 3] + (nx & 7) * 32, 256, sB[nx & 1], w, lane);
    }
    mfma_tiles(sA[c & 1], sB[c & 1], acc, wr, wc, lane);
    __syncthreads();
  }

  int q = lane >> 4, cc16 = lane & 15;
  bool ev = (lane & 1) == 0;
  float c0v[4], tWgv[4];
#pragma unroll
  for (int ni = 0; ni < 4; ++ni) {
    int j = tn * 128 + wc * 64 + ni * 16 + cc16;
    c0v[ni] = c0[j];
    tWgv[ni] = tWg[j];
  }
  bool eblk = (tm == 0) && (wr == 0) && (q == 0);
  u16* obase = outp + (size_t)bt * 65536;
#pragma unroll
  for (int mi = 0; mi < 4; ++mi) {
    int row0 = tm * 128 + wr * 64 + mi * 16 + q * 4;
#pragma unroll
    for (int ni = 0; ni < 4; ++ni) {
      float v[4];
#pragma unroll
      for (int r = 0; r < 4; ++r) v[r] = acc[mi][ni][r] + c0v[ni];
      int colb = tn * 128 + wc * 64 + ni * 16 + (cc16 & ~1);
      store_pairs(obase, row0, 256, colb, v, ev);
      if (eblk && mi == 0) {
        float vE[4];
#pragma unroll
        for (int r = 0; r < 4; ++r) vE[r] = acc[0][ni][r] + tWgv[ni];
        store_pairs_f32(edge + (size_t)bt * 1024, 0, 256, colb, vE, ev);
      }
    }
  }
}

// ---- fixup: overwrite p<4 nodes with GCN aggregation (closed-form dinv) ----
__device__ __forceinline__ float dinv0(int t) {
  if (t == 0) return 0.44721359549995793f;   // 1/sqrt(5)
  if (t == 127) return 0.7071067811865476f;  // 1/sqrt(2)
  return 0.4082482904638631f;                // 1/sqrt(6)
}
__global__ __launch_bounds__(256) void k_fix(const float* __restrict__ edge, const float* __restrict__ bg,
                                             u16* __restrict__ outp) {
  int bt = blockIdx.x;
  int t = bt & 127;
  int j = threadIdx.x;
  const float ISQ2 = 0.7071067811865476f;
  float bgv = bg[j];
  float e_t = edge[(size_t)bt * 1024 + j];
  float At = dinv0(t);
  float o0 = bgv + At * At * e_t;
  if (t <= 126) {
    float At1 = dinv0(t + 1);
    const float* en = edge + (size_t)(bt + 1) * 1024;
    float s = At1 * en[j] + ISQ2 * (en[256 + j] + en[512 + j] + en[768 + j]);
    o0 += At * s;
  }
  float em1 = 0.f, Atm1 = 0.f;
  if (t >= 1) {
    Atm1 = dinv0(t - 1);
    em1 = edge[(size_t)(bt - 1) * 1024 + j];
    o0 += At * Atm1 * em1;
  }
  u16* ob = outp + (size_t)bt * 65536;
  ob[j] = f2b(o0);
#pragma unroll
  for (int k = 1; k <= 3; ++k) {
    float m = edge[(size_t)bt * 1024 + k * 256 + j];
    float ok = (t == 0) ? (bgv + m) : (bgv + 0.5f * m + ISQ2 * Atm1 * em1);
    ob[k * 256 + j] = f2b(ok);
  }
}

// ---- G3: y[bt][co][p] = tconv2(out)*s2 + t2  (m=co, n=p), fp32 out ----
__global__ __launch_bounds__(256) void k_g3(const u16* __restrict__ outp, const u16* __restrict__ Wup,
                                            const float* __restrict__ s2, const float* __restrict__ t2,
                                            float* __restrict__ y) {
  __shared__ u16 sA[2][128 * 32];
  __shared__ u16 sB[2][128 * 32];
  __shared__ float ss2[128], st2[128];
  int b = blockIdx.x;
  int logical = (b & 7) * 256 + (b >> 3);
  int bt = logical >> 2;
  int tile = logical & 3;
  int tm = tile >> 1, tn = tile & 1;
  int t = bt & 127;
  int tid = threadIdx.x, lane = tid & 63, w = tid >> 6;
  int wr = w >> 1, wc = w & 1;
  if (tid < 128) {
    int co = tm * 128 + tid;
    ss2[tid] = s2[co];
    st2[tid] = t2[co];
  }
  f32x4 acc[4][4];
#pragma unroll
  for (int i = 0; i < 4; ++i)
#pragma unroll
    for (int j = 0; j < 4; ++j) acc[i][j] = (f32x4){0.f, 0.f, 0.f, 0.f};

  const u16* Ap[3];
  const u16* Bp[3];
  int nf = 0;
#pragma unroll
  for (int kk = 0; kk < 3; ++kk) {
    int tp = t - 1 + kk;
    if (tp < 0 || tp > 127) continue;
    Ap[nf] = Wup + (size_t)kk * 65536 + (size_t)(tm * 128) * 256;
    Bp[nf] = outp + ((size_t)(bt - t + tp) * 256 + tn * 128) * 256;
    ++nf;
  }
  int nc = nf * 8;
  stage_tile(Ap[0], 256, sA[0], w, lane);
  stage_tile(Bp[0], 256, sB[0], w, lane);
  __syncthreads();
  for (int c = 0; c < nc; ++c) {
    int nx = c + 1;
    if (nx < nc) {
      stage_tile(Ap[nx >> 3] + (nx & 7) * 32, 256, sA[nx & 1], w, lane);
      stage_tile(Bp[nx >> 3] + (nx & 7) * 32, 256, sB[nx & 1], w, lane);
    }
    mfma_tiles(sA[c & 1], sB[c & 1], acc, wr, wc, lane);
    __syncthreads();
  }

  int q = lane >> 4, cc16 = lane & 15;
  bool ev = (lane & 1) == 0;
  float* ybase = y + (size_t)bt * 65536;
#pragma unroll
  for (int mi = 0; mi < 4; ++mi) {
    int rl = wr * 64 + mi * 16 + q * 4;
    float sv[4], tv[4];
#pragma unroll
    for (int r = 0; r < 4; ++r) { sv[r] = ss2[rl + r]; tv[r] = st2[rl + r]; }
#pragma unroll
    for (int ni = 0; ni < 4; ++ni) {
      float v[4];
#pragma unroll
      for (int r = 0; r < 4; ++r) v[r] = acc[mi][ni][r] * sv[r] + tv[r];
      int colb = tn * 128 + wc * 64 + ni * 16 + (cc16 & ~1);
      store_pairs_f32(ybase, tm * 128 + rl, 256, colb, v, ev);
    }
  }
}

extern "C" void kernel_launch(void* const* d_in, const int* in_sizes, int n_in,
                              void* d_out, int out_size, void* d_ws, size_t ws_size,
                              hipStream_t stream) {
  (void)in_sizes; (void)n_in; (void)out_size; (void)ws_size;
  const float* x  = (const float*)d_in[0];
  const float* Wd = (const float*)d_in[2];
  const float* s1 = (const float*)d_in[3];
  const float* t1 = (const float*)d_in[4];
  const float* Wg = (const float*)d_in[5];
  const float* bg = (const float*)d_in[6];
  const float* Wu = (const float*)d_in[7];
  const float* s2 = (const float*)d_in[8];
  const float* t2 = (const float*)d_in[9];
  float* y = (float*)d_out;
  char* ws = (char*)d_ws;
  u16*   outp  = (u16*)(ws);                    // 64 MiB bf16
  u16*   xT    = (u16*)(ws + 67108864);         // 64 MiB bf16
  float* edge  = (float*)(ws + 134217728);      // 2 MiB fp32 (overlays WdT/WgS, dead after wcomb)
  u16*   WdT   = (u16*)(ws + 134217728);        // 384 KiB
  u16*   WgS   = (u16*)(ws + 134611072);        // 128 KiB
  u16*   Wup   = (u16*)(ws + 136314880);        // 384 KiB
  u16*   Wcomb = (u16*)(ws + 136708096);        // 384 KiB
  float* c0    = (float*)(ws + 137101312);      // 1 KiB
  float* tWg   = (float*)(ws + 137102336);      // 1 KiB

  k_prep<<<dim3(1025), dim3(256), 0, stream>>>(Wd, Wg, Wu, s1, t1, bg, WdT, Wup, WgS, c0, tWg);
  k_wcomb<<<dim3(12), dim3(256), 0, stream>>>(WgS, WdT, Wcomb);
  k_transpose<<<dim3(8192), dim3(256), 0, stream>>>(x, xT);
  k_g12<<<dim3(2048), dim3(256), 0, stream>>>(xT, Wcomb, c0, tWg, outp, edge);
  k_fix<<<dim3(512), dim3(256), 0, stream>>>(edge, bg, outp);
  k_g3<<<dim3(2048), dim3(256), 0, stream>>>(outp, Wup, s2, t2, y);
}